// Round 7
// baseline (62.993 us; speedup 1.0000x reference)
//
#include <hip/hip_runtime.h>

// Segmented histogram: out[g, c] = sum of w[i] for i in [ptr[g], ptr[g+1])
// with x[i] == c < out_dim.
//
// Rounds 1-5: five structures, all 48-60us, all counters idle -> limiter is
// per-wave memory-level-parallelism duty cycle. This version is the cleanest
// max-MLP shape: ONE tile (2048 nodes) per WAVE, all 16 dwordx4 loads issued
// back-to-back at wave start (pinned first via sched_barrier), graph search
// overlapped on the scalar path (s_load / lgkmcnt, never touching vmcnt),
// then a single bin+flush pass. No barriers, no loop-carried state.
// Round-6 fix: force wave-uniform SGPR operands for the inline s_load via
// readfirstlane (clang had materialized a VGPR into the "s" slot).

#define TILE  2048              // nodes per wave
#define ODIM  256

// Scalar load p[idx] via s_load (lgkmcnt path; never touches vmcnt).
// idx must be wave-uniform in value; readfirstlane forces it into an SGPR.
__device__ __forceinline__ int sload_i32(const int* p, int idx) {
    const int off = __builtin_amdgcn_readfirstlane(idx * 4);
    int v;
    asm volatile("s_load_dword %0, %1, %2\n\ts_waitcnt lgkmcnt(0)"
                 : "=&s"(v)
                 : "s"(p), "s"(off));
    return v;
}

extern "C" __global__ __launch_bounds__(256, 4)
void hist_kernel(const int* __restrict__ x, const int* __restrict__ ptr,
                 const float* __restrict__ w, float* __restrict__ out,
                 int n_nodes, int num_graphs) {
    __shared__ float hist[4][ODIM];

    const int wv   = (int)threadIdx.x >> 6;
    const int lane = (int)threadIdx.x & 63;
    float* h = hist[wv];

    const int n_tiles     = (n_nodes + TILE - 1) / TILE;
    const int total_waves = (int)gridDim.x * 4;

    for (int T = (int)blockIdx.x * 4 + wv; T < n_tiles; T += total_waves) {
        const int A = __builtin_amdgcn_readfirstlane(T * TILE);
        const int B = min(A + TILE, n_nodes);

        // ---- phase 0: issue ALL data loads back-to-back (32 nodes/lane) ----
        int4   X[8];
        float4 W[8];
        const int labs = A + lane * 4;  // lane's group-k nodes: labs + k*256 .. +3
        if (B - A == TILE) {
            #pragma unroll
            for (int k = 0; k < 8; ++k) {
                X[k] = *reinterpret_cast<const int4*>(x + labs + (k << 8));
                W[k] = *reinterpret_cast<const float4*>(w + labs + (k << 8));
            }
        } else {
            // tail tile: guarded per-element loads
            #pragma unroll
            for (int k = 0; k < 8; ++k) {
                int l[4]; float ww[4];
                #pragma unroll
                for (int m = 0; m < 4; ++m) {
                    const int ii = labs + (k << 8) + m;
                    if (ii < n_nodes) { l[m] = x[ii]; ww[m] = w[ii]; }
                    else              { l[m] = 0x7fffffff; ww[m] = 0.0f; }
                }
                X[k] = make_int4(l[0], l[1], l[2], l[3]);
                W[k] = make_float4(ww[0], ww[1], ww[2], ww[3]);
            }
        }
        // pin the load burst ahead of everything that follows
        __builtin_amdgcn_sched_barrier(0);

        // ---- phase 1 (overlaps load latency): zero hist + scalar search ----
        #pragma unroll
        for (int kk = 0; kk < 4; ++kk) h[lane + (kk << 6)] = 0.0f;

        // g0 = last j with ptr[j] <= A  (wave-uniform scalar binary search)
        int lo = 0, hi = num_graphs - 1;
        while (lo < hi) {
            const int mid = (lo + hi + 1) >> 1;
            if (sload_i32(ptr, mid) <= A) lo = mid; else hi = mid - 1;
        }
        int j = __builtin_amdgcn_readfirstlane(lo);
        int pstart = sload_i32(ptr, j);

        // ---- phase 2: walk graph pieces, bin from registers, flush ----
        for (;;) {
            const int pend = sload_i32(ptr, j + 1);
            const int s = max(pstart, A);
            const int e = min(pend, B);

            if (s < e) {
                #pragma unroll
                for (int k = 0; k < 8; ++k) {
                    const int i0 = labs + (k << 8);
                    if (i0 < e && i0 + 4 > s) {
#define ADDM(LBL, WV, M)                                                   \
                        { const int ii = i0 + (M);                         \
                          if (ii >= s && ii < e &&                         \
                              (unsigned)(LBL) < (unsigned)ODIM)            \
                              atomicAdd(&h[LBL], (WV)); }
                        ADDM(X[k].x, W[k].x, 0) ADDM(X[k].y, W[k].y, 1)
                        ADDM(X[k].z, W[k].z, 2) ADDM(X[k].w, W[k].w, 3)
#undef ADDM
                    }
                }
            }

            // flush row j (4 bins per lane) and re-zero
            const bool whole = (pstart >= A) && (pend <= B);
            float* row = out + (size_t)j * ODIM;
            #pragma unroll
            for (int kk = 0; kk < 4; ++kk) {
                const int bin = lane + (kk << 6);
                const float v = h[bin];
                if (whole)          row[bin] = v;
                else if (v != 0.0f) atomicAdd(&row[bin], v);
                h[bin] = 0.0f;
            }

            if (pend >= B) break;
            ++j; pstart = pend;
        }
    }
}

// Generic fallback (round-1 structure) for out_dim != 256.
extern "C" __global__ __launch_bounds__(256)
void seg_hist_fallback(const int* __restrict__ x, const int* __restrict__ ptr,
                       const float* __restrict__ w, float* __restrict__ out,
                       int out_dim) {
    extern __shared__ float fhist[];
    const int g = blockIdx.x;
    const int start = ptr[g];
    const int end = ptr[g + 1];
    for (int c = (int)threadIdx.x; c < out_dim; c += 256) fhist[c] = 0.0f;
    __syncthreads();
    for (int i = start + (int)threadIdx.x; i < end; i += 256) {
        const int lbl = x[i];
        if ((unsigned)lbl < (unsigned)out_dim) atomicAdd(&fhist[lbl], w[i]);
    }
    __syncthreads();
    float* o = out + (size_t)g * (size_t)out_dim;
    for (int c = (int)threadIdx.x; c < out_dim; c += 256) o[c] = fhist[c];
}

extern "C" void kernel_launch(void* const* d_in, const int* in_sizes, int n_in,
                              void* d_out, int out_size, void* d_ws, size_t ws_size,
                              hipStream_t stream) {
    const int* x   = (const int*)d_in[0];
    const int* ptr = (const int*)d_in[1];
    const float* w = (const float*)d_in[2];
    float* out     = (float*)d_out;

    const int n_nodes    = in_sizes[0];
    const int num_graphs = in_sizes[1] - 1;
    const int out_dim    = out_size / num_graphs;

    if (out_dim != ODIM) {
        seg_hist_fallback<<<num_graphs, 256, (size_t)out_dim * sizeof(float), stream>>>(
            x, ptr, w, out, out_dim);
        return;
    }

    // zero output (straddler flushes accumulate onto it; covers empty graphs)
    hipMemsetAsync(d_out, 0, (size_t)out_size * sizeof(float), stream);

    const int n_tiles = (n_nodes + TILE - 1) / TILE;
    const int n_blocks = (n_tiles + 3) / 4;   // one tile per wave, 4 waves/block
    hist_kernel<<<n_blocks, 256, 0, stream>>>(x, ptr, w, out, n_nodes, num_graphs);
}

// Round 8
// 52.681 us; speedup vs baseline: 1.1957x; 1.1957x over previous
//
#include <hip/hip_runtime.h>

// Segmented histogram: out[g, c] = sum of w[i] for i in [ptr[g], ptr[g+1])
// with x[i] == c < out_dim.
//
// Round-7 falsifications: not latency-bound (half the waves, same time), not
// HBM-bound (L3-resident replays, same time), not VALU/LDS/atomic-bound (all
// idle). Remaining lever: minimize serial dependent memory phases per work
// unit. This version: ONE WAVE PER GRAPH.
//   - 2 scalar ptr loads (uniform index -> s_load, compiler-scalarized)
//   - vectorized int4/float4 segment read (scalar head/tail for alignment)
//   - per-wave private 1 KB LDS hist, no barriers anywhere
//   - direct row store: no global atomics, no memset, no setup kernel,
//     no binary search. Empty graphs naturally store zeros.
// Serial chain per wave ~3 round trips - the minimum this op permits.

#define ODIM 256

extern "C" __global__ __launch_bounds__(256, 8)
void wave_hist_kernel(const int* __restrict__ x, const int* __restrict__ ptr,
                      const float* __restrict__ w, float* __restrict__ out,
                      int num_graphs) {
    __shared__ float hist[4][ODIM];

    const int wv   = (int)threadIdx.x >> 6;
    const int lane = (int)threadIdx.x & 63;
    float* h = hist[wv];

    const int total_waves = (int)gridDim.x * 4;

    for (int g = (int)blockIdx.x * 4 + wv; g < num_graphs; g += total_waves) {
        const int s = ptr[g];
        const int e = ptr[g + 1];

        // zero private hist (wave-private: no barrier; in-order DS ops)
        #pragma unroll
        for (int k = 0; k < 4; ++k) h[lane + (k << 6)] = 0.0f;

        // alignment split: head [s,a0) | body [a0,a1) 16B-aligned | tail [a1,e)
        const int a0 = min((s + 3) & ~3, e);
        const int a1 = max(e & ~3, a0);

        // head (<=3 nodes)
        {
            const int i = s + lane;
            if (i < a0) {
                const int lbl = x[i];
                if ((unsigned)lbl < (unsigned)ODIM) atomicAdd(&h[lbl], w[i]);
            }
        }

        // body: 4 nodes/lane/iter, coalesced dwordx4
        for (int i = a0 + lane * 4; i < a1; i += 64 * 4) {
            const int4   l4 = *reinterpret_cast<const int4*>(x + i);
            const float4 w4 = *reinterpret_cast<const float4*>(w + i);
            if ((unsigned)l4.x < (unsigned)ODIM) atomicAdd(&h[l4.x], w4.x);
            if ((unsigned)l4.y < (unsigned)ODIM) atomicAdd(&h[l4.y], w4.y);
            if ((unsigned)l4.z < (unsigned)ODIM) atomicAdd(&h[l4.z], w4.z);
            if ((unsigned)l4.w < (unsigned)ODIM) atomicAdd(&h[l4.w], w4.w);
        }

        // tail (<=3 nodes)
        {
            const int i = a1 + lane;
            if (i < e) {
                const int lbl = x[i];
                if ((unsigned)lbl < (unsigned)ODIM) atomicAdd(&h[lbl], w[i]);
            }
        }

        // exclusive row store (covers empty graphs with zeros)
        float* row = out + (size_t)g * ODIM;
        #pragma unroll
        for (int k = 0; k < 4; ++k) row[lane + (k << 6)] = h[lane + (k << 6)];
    }
}

// Generic fallback for out_dim != 256 (round-1 structure).
extern "C" __global__ __launch_bounds__(256)
void seg_hist_fallback(const int* __restrict__ x, const int* __restrict__ ptr,
                       const float* __restrict__ w, float* __restrict__ out,
                       int out_dim) {
    extern __shared__ float fhist[];
    const int g = blockIdx.x;
    const int start = ptr[g];
    const int end = ptr[g + 1];
    for (int c = (int)threadIdx.x; c < out_dim; c += 256) fhist[c] = 0.0f;
    __syncthreads();
    for (int i = start + (int)threadIdx.x; i < end; i += 256) {
        const int lbl = x[i];
        if ((unsigned)lbl < (unsigned)out_dim) atomicAdd(&fhist[lbl], w[i]);
    }
    __syncthreads();
    float* o = out + (size_t)g * (size_t)out_dim;
    for (int c = (int)threadIdx.x; c < out_dim; c += 256) o[c] = fhist[c];
}

extern "C" void kernel_launch(void* const* d_in, const int* in_sizes, int n_in,
                              void* d_out, int out_size, void* d_ws, size_t ws_size,
                              hipStream_t stream) {
    const int* x   = (const int*)d_in[0];
    const int* ptr = (const int*)d_in[1];
    const float* w = (const float*)d_in[2];
    float* out     = (float*)d_out;

    const int num_graphs = in_sizes[1] - 1;
    const int out_dim    = out_size / num_graphs;

    if (out_dim != ODIM) {
        seg_hist_fallback<<<num_graphs, 256, (size_t)out_dim * sizeof(float), stream>>>(
            x, ptr, w, out, out_dim);
        return;
    }

    // one wave per graph; 4 waves per 256-thread block
    const int n_blocks = (num_graphs + 3) / 4;
    wave_hist_kernel<<<n_blocks, 256, 0, stream>>>(x, ptr, w, out, num_graphs);
}